// Round 2
// baseline (99.101 us; speedup 1.0000x reference)
//
#include <hip/hip_runtime.h>
#include <math.h>

// Reference collapses to: out[b] = MLP( softmax_t( q0[b]*k[b,t] + bias[0,0,t] ) · v[b,t] )
// since the reference returns y[0,:,0] (only s=0 survives).
// S=2048, B=32, H=1, MLP_HID=256, OUT_DIM=1.
//
// Single block, 1024 threads. tid -> (g = tid>>5, b = tid&31).
// src is [S,B] row-major: element (t,b) at index t*32+b. With t = g + 32*i,
// idx = (g+32i)*32 + b = tid + 1024*i  ->  perfectly coalesced loads.
// Two passes over src (256 KB, L2-resident after the harness restore copy):
// pass A = global max of scores, pass B = exp-sum and weighted v-sum.

constexpr int S   = 2048;
constexpr int B   = 32;
constexpr int TPB = 1024;
constexpr int NW  = TPB / 64;   // 16 waves
constexpr int ITER = S / (TPB / B);  // 64 t-values per thread

__global__ __launch_bounds__(TPB) void fused_transformer_row0(
    const float* __restrict__ src,   // [S, B]
    const float* __restrict__ Wq, const float* __restrict__ bq,
    const float* __restrict__ Wk, const float* __restrict__ bk,
    const float* __restrict__ Wv, const float* __restrict__ bv,
    const float* __restrict__ bias,  // [1, S, S]; only bias[0,0,t] used
    const float* __restrict__ W1,    // [256,1]
    const float* __restrict__ b1,    // [256]
    const float* __restrict__ W2,    // [1,256]
    const float* __restrict__ b2,    // [1]
    float* __restrict__ out)         // [B]
{
    const int tid  = threadIdx.x;
    const int b    = tid & 31;
    const int g    = tid >> 5;       // 0..31: which t-stripe / which m-stripe
    const int lane = tid & 63;
    const int wave = tid >> 6;       // 0..15

    __shared__ float redA[NW * 32];  // per-wave, per-b partials
    __shared__ float redB[NW * 32];
    __shared__ float finM[32];
    __shared__ float finCtx[32];

    const float wq  = Wq[0], wk = Wk[0], wv = Wv[0];
    const float bq0 = bq[0], bk0 = bk[0], bv0 = bv[0];
    const float qb  = src[b] * wq + bq0;       // src[0*B + b]

    // ---- pass A: max over t of score(b,t) ----
    float mloc = -INFINITY;
#pragma unroll 8
    for (int i = 0; i < ITER; ++i) {
        const int idx = tid + TPB * i;         // (g+32i)*32 + b
        const int t   = g + 32 * i;
        const float x = src[idx];
        const float s = qb * (x * wk + bk0) + bias[t];
        mloc = fmaxf(mloc, s);
    }
    // lanes l and l+32 share the same b
    mloc = fmaxf(mloc, __shfl_down(mloc, 32, 64));
    if (lane < 32) redA[wave * 32 + b] = mloc;
    __syncthreads();
    if (tid < 32) {
        float m = redA[tid];
        for (int w = 1; w < NW; ++w) m = fmaxf(m, redA[w * 32 + tid]);
        finM[tid] = m;
    }
    __syncthreads();
    const float gmax = finM[b];

    // ---- pass B: exp-sum and weighted v-sum ----
    float lsum = 0.f, csum = 0.f;
#pragma unroll 8
    for (int i = 0; i < ITER; ++i) {
        const int idx = tid + TPB * i;
        const int t   = g + 32 * i;
        const float x = src[idx];
        const float s = qb * (x * wk + bk0) + bias[t];
        const float e = __expf(s - gmax);
        lsum += e;
        csum += e * (x * wv + bv0);
    }
    lsum += __shfl_down(lsum, 32, 64);
    csum += __shfl_down(csum, 32, 64);
    __syncthreads();                 // redA reuse barrier
    if (lane < 32) { redA[wave * 32 + b] = lsum; redB[wave * 32 + b] = csum; }
    __syncthreads();
    if (tid < 32) {
        float L = 0.f, C = 0.f;
        for (int w = 0; w < NW; ++w) { L += redA[w * 32 + tid]; C += redB[w * 32 + tid]; }
        finCtx[tid] = C / L;
    }
    __syncthreads();
    const float ctx = finCtx[b];

    // ---- MLP: thread (b,g) handles hidden units m = g + 32j, j=0..7 ----
    float term = 0.f;
#pragma unroll
    for (int j = 0; j < 8; ++j) {
        const int m   = g + 32 * j;
        const float h = fmaxf(ctx * W1[m] + b1[m], 0.f);
        term += h * W2[m];
    }
    term += __shfl_down(term, 32, 64);
    __syncthreads();                 // redA reuse barrier
    if (lane < 32) redA[wave * 32 + b] = term;
    __syncthreads();
    if (tid < 32) {
        float s = 0.f;
        for (int w = 0; w < NW; ++w) s += redA[w * 32 + tid];
        out[tid] = s + b2[0];
    }
}

extern "C" void kernel_launch(void* const* d_in, const int* in_sizes, int n_in,
                              void* d_out, int out_size, void* d_ws, size_t ws_size,
                              hipStream_t stream) {
    const float* src  = (const float*)d_in[0];
    const float* Wq   = (const float*)d_in[1];
    const float* bq   = (const float*)d_in[2];
    const float* Wk   = (const float*)d_in[3];
    const float* bk   = (const float*)d_in[4];
    const float* Wv   = (const float*)d_in[5];
    const float* bv   = (const float*)d_in[6];
    const float* bias = (const float*)d_in[7];
    const float* W1   = (const float*)d_in[8];
    const float* b1   = (const float*)d_in[9];
    const float* W2   = (const float*)d_in[10];
    const float* b2   = (const float*)d_in[11];
    float* out = (float*)d_out;

    fused_transformer_row0<<<1, TPB, 0, stream>>>(
        src, Wq, bq, Wk, bk, Wv, bv, bias, W1, b1, W2, b2, out);
}

// Round 3
// 87.737 us; speedup vs baseline: 1.1295x; 1.1295x over previous
//
#include <hip/hip_runtime.h>
#include <math.h>

// Reference returns y[0,:,0] -> only s=0 of the attention output survives:
//   out[b] = MLP( softmax_t( q0[b]*k[b,t] + bias[0,0,t] ) . v[b,t] )
// S=2048, B=32, H=1, MLP_HID=256, OUT_DIM=1.
//
// Mapping (best measured, R1): one block per batch element b -> 32 CUs work
// in parallel. src (256 KB) is L2/L3-hot after the harness restore copy, so
// the column-strided reads cost L2 latency only; 8 waves/block + 4
// independent loads/thread hide it. Scores/values stay in registers between
// the max pass and the exp pass (no reloads).

constexpr int S   = 2048;
constexpr int B   = 32;
constexpr int TPB = 512;      // threads per block
constexpr int NW  = TPB / 64; // 8 waves
constexpr int TPT = S / TPB;  // 4 t-values per thread

__global__ __launch_bounds__(TPB) void fused_transformer_row0(
    const float* __restrict__ src,   // [S, B]
    const float* __restrict__ Wq, const float* __restrict__ bq,
    const float* __restrict__ Wk, const float* __restrict__ bk,
    const float* __restrict__ Wv, const float* __restrict__ bv,
    const float* __restrict__ bias,  // [1, S, S]; only bias[0,0,t] used
    const float* __restrict__ W1,    // [256,1]
    const float* __restrict__ b1,    // [256]
    const float* __restrict__ W2,    // [1,256]
    const float* __restrict__ b2,    // [1]
    float* __restrict__ out)         // [B]
{
    const int b    = blockIdx.x;
    const int tid  = threadIdx.x;
    const int lane = tid & 63;
    const int wave = tid >> 6;

    __shared__ float redm[NW], redl[NW], redc[NW], redy[NW];

    const float wq  = Wq[0], wk = Wk[0], wv = Wv[0];
    const float bk0 = bk[0], bv0 = bv[0];
    const float qb  = src[b] * wq + bq[0];     // q at s=0

    // ---- scores & v for TPT t-positions, tracking local max ----
    float sc[TPT], vv[TPT];
    float mloc = -INFINITY;
#pragma unroll
    for (int i = 0; i < TPT; ++i) {
        const int t   = tid + i * TPB;
        const float x = src[t * B + b];
        sc[i] = qb * (x * wk + bk0) + bias[t];
        vv[i] = x * wv + bv0;
        mloc  = fmaxf(mloc, sc[i]);
    }
#pragma unroll
    for (int off = 32; off > 0; off >>= 1)
        mloc = fmaxf(mloc, __shfl_down(mloc, off, 64));
    if (lane == 0) redm[wave] = mloc;
    __syncthreads();
    float gmax = redm[0];
#pragma unroll
    for (int w = 1; w < NW; ++w) gmax = fmaxf(gmax, redm[w]);

    // ---- exp-sum and weighted v-sum (registers, no reloads) ----
    float lsum = 0.f, csum = 0.f;
#pragma unroll
    for (int i = 0; i < TPT; ++i) {
        const float e = __expf(sc[i] - gmax);
        lsum += e;
        csum += e * vv[i];
    }
#pragma unroll
    for (int off = 32; off > 0; off >>= 1) {
        lsum += __shfl_down(lsum, off, 64);
        csum += __shfl_down(csum, off, 64);
    }
    if (lane == 0) { redl[wave] = lsum; redc[wave] = csum; }
    __syncthreads();
    float L = 0.f, C = 0.f;
#pragma unroll
    for (int w = 0; w < NW; ++w) { L += redl[w]; C += redc[w]; }
    const float ctx = C / L;

    // ---- MLP: first 256 threads each handle one hidden unit ----
    float term = 0.f;
    if (tid < 256) {
        const float h = fmaxf(ctx * W1[tid] + b1[tid], 0.f);
        term = h * W2[tid];
    }
#pragma unroll
    for (int off = 32; off > 0; off >>= 1)
        term += __shfl_down(term, off, 64);
    if (lane == 0) redy[wave] = term;
    __syncthreads();
    if (tid == 0) {
        float y = b2[0];
#pragma unroll
        for (int w = 0; w < NW; ++w) y += redy[w];
        out[b] = y;
    }
}

extern "C" void kernel_launch(void* const* d_in, const int* in_sizes, int n_in,
                              void* d_out, int out_size, void* d_ws, size_t ws_size,
                              hipStream_t stream) {
    const float* src  = (const float*)d_in[0];
    const float* Wq   = (const float*)d_in[1];
    const float* bq   = (const float*)d_in[2];
    const float* Wk   = (const float*)d_in[3];
    const float* bk   = (const float*)d_in[4];
    const float* Wv   = (const float*)d_in[5];
    const float* bv   = (const float*)d_in[6];
    const float* bias = (const float*)d_in[7];
    const float* W1   = (const float*)d_in[8];
    const float* b1   = (const float*)d_in[9];
    const float* W2   = (const float*)d_in[10];
    const float* b2   = (const float*)d_in[11];
    float* out = (float*)d_out;

    fused_transformer_row0<<<B, TPB, 0, stream>>>(
        src, Wq, bq, Wk, bk, Wv, bv, bias, W1, b1, W2, b2, out);
}